// Round 4
// baseline (616.510 us; speedup 1.0000x reference)
//
#include <hip/hip_runtime.h>
#include <hip/hip_bf16.h>
#include <math.h>

#define NTOK 8192
#define DM   1024
#define NE   16
#define HD   4096
#define CAP  640

typedef float f32x4 __attribute__((ext_vector_type(4)));
typedef _Float16 f16x8 __attribute__((ext_vector_type(8)));
typedef _Float16 f16x4 __attribute__((ext_vector_type(4)));

__device__ __forceinline__ void gload16(const void* g, void* l) {
  __builtin_amdgcn_global_load_lds(
      (const __attribute__((address_space(1))) unsigned int*)g,
      (__attribute__((address_space(3))) unsigned int*)l, 16, 0, 0);
}

// ---------------- router: logits + softmax + col partials (one wave/token) ----------------
__global__ __launch_bounds__(256) void k_router(const float* __restrict__ x,
                                                const float* __restrict__ Wr,
                                                float* __restrict__ probs,
                                                float* __restrict__ pout) {
  int wave = threadIdx.x >> 6, lane = threadIdx.x & 63;
  int tok = blockIdx.x * 4 + wave;
  const float* xr = x + (size_t)tok * DM;
  float acc[NE];
#pragma unroll
  for (int e = 0; e < NE; ++e) acc[e] = 0.f;
  for (int d = lane; d < DM; d += 64) {
    float xv = xr[d];
    const float* w = Wr + (size_t)d * NE;
#pragma unroll
    for (int e = 0; e < NE; ++e) acc[e] = fmaf(xv, w[e], acc[e]);
  }
#pragma unroll
  for (int off = 32; off >= 1; off >>= 1) {
#pragma unroll
    for (int e = 0; e < NE; ++e) acc[e] += __shfl_xor(acc[e], off, 64);
  }
  float m = acc[0];
#pragma unroll
  for (int e = 1; e < NE; ++e) m = fmaxf(m, acc[e]);
  float s = 0.f;
#pragma unroll
  for (int e = 0; e < NE; ++e) { acc[e] = expf(acc[e] - m); s += acc[e]; }
  float inv = 1.0f / s;
#pragma unroll
  for (int e = 0; e < NE; ++e) acc[e] *= inv;
  if (lane < NE) probs[(size_t)tok * NE + lane] = acc[lane];
  __shared__ float wsum[4][NE];
  if (lane == 0) {
#pragma unroll
    for (int e = 0; e < NE; ++e) wsum[wave][e] = acc[e];
  }
  __syncthreads();
  if (threadIdx.x < NE)
    pout[blockIdx.x * NE + threadIdx.x] =
        wsum[0][threadIdx.x] + wsum[1][threadIdx.x] + wsum[2][threadIdx.x] + wsum[3][threadIdx.x];
}

// ------------- fused sinkhorn step: col-normalize, row-normalize, emit col partials -------------
__global__ __launch_bounds__(256) void k_sink(float* __restrict__ probs,
                                              const float* __restrict__ pin,
                                              float* __restrict__ pout) {
  __shared__ float csinv[NE];
  int tid = threadIdx.x;
  if (tid < NE) {
    float s = 0.f;
#pragma unroll
    for (int b = 0; b < 32; ++b) s += pin[b * NE + tid];
    csinv[tid] = 512.0f / s;
  }
  __syncthreads();
  int tok = blockIdx.x * 256 + tid;
  float* row = probs + (size_t)tok * NE;
  float p[NE]; float rs = 0.f;
#pragma unroll
  for (int e = 0; e < NE; ++e) { p[e] = row[e] * csinv[e]; rs += p[e]; }
  float rinv = 1.0f / rs;
#pragma unroll
  for (int e = 0; e < NE; ++e) { p[e] *= rinv; row[e] = p[e]; }
#pragma unroll
  for (int off = 32; off >= 1; off >>= 1) {
#pragma unroll
    for (int e = 0; e < NE; ++e) p[e] += __shfl_xor(p[e], off, 64);
  }
  __shared__ float wsum[4][NE];
  int lane = tid & 63, wave = tid >> 6;
  if (lane == 0) {
#pragma unroll
    for (int e = 0; e < NE; ++e) wsum[wave][e] = p[e];
  }
  __syncthreads();
  if (tid < NE)
    pout[blockIdx.x * NE + tid] =
        wsum[0][tid] + wsum[1][tid] + wsum[2][tid] + wsum[3][tid];
}

// ------------- final sinkhorn col-normalize fused with top-2 + weight renorm -------------
__global__ __launch_bounds__(256) void k_sink3(const float* __restrict__ probs,
                                               const float* __restrict__ pin,
                                               int* __restrict__ eidx,
                                               float* __restrict__ ew) {
  __shared__ float csinv[NE];
  int tid = threadIdx.x;
  if (tid < NE) {
    float s = 0.f;
#pragma unroll
    for (int b = 0; b < 32; ++b) s += pin[b * NE + tid];
    csinv[tid] = 512.0f / s;
  }
  __syncthreads();
  int tok = blockIdx.x * 256 + tid;
  const float* row = probs + (size_t)tok * NE;
  float v0 = -1e30f, v1 = -1e30f; int e0 = 0, e1 = 0;
#pragma unroll
  for (int e = 0; e < NE; ++e) {
    float v = row[e] * csinv[e];
    if (v > v0) { v1 = v0; e1 = e0; v0 = v; e0 = e; }
    else if (v > v1) { v1 = v; e1 = e; }
  }
  float s = v0 + v1;
  eidx[tok * 2] = e0; eidx[tok * 2 + 1] = e1;
  ew[tok * 2] = v0 / s; ew[tok * 2 + 1] = v1 / s;
}

// ------------- sequential (t,k)-order slot allocation: one block per expert -------------
__global__ __launch_bounds__(256) void k_scan(const int* __restrict__ eidx,
                                              const float* __restrict__ ew,
                                              int* __restrict__ slot_tok,
                                              float* __restrict__ slot_w,
                                              int* __restrict__ counts) {
  int e = blockIdx.x;
  int tid = threadIdx.x, lane = tid & 63, wave = tid >> 6;
  __shared__ int wtot[4];
  int running = 0;
  for (int base = 0; base < NTOK * 2; base += 256) {
    int i = base + tid;
    int match = (eidx[i] == e) ? 1 : 0;
    unsigned long long mb = __ballot(match);
    if (lane == 0) wtot[wave] = __popcll(mb);
    __syncthreads();
    int pre = 0;
    for (int w = 0; w < wave; ++w) pre += wtot[w];
    int tot = wtot[0] + wtot[1] + wtot[2] + wtot[3];
    if (match) {
      int pos = running + pre + __popcll(mb & ((1ull << lane) - 1ull));
      if (pos < CAP) {
        slot_tok[e * CAP + pos] = i >> 1;
        slot_w[e * CAP + pos] = ew[i];
      }
    }
    running += tot;
    __syncthreads();
  }
  if (tid == 0) counts[e] = running;
}

__global__ void k_aux(const int* __restrict__ counts, float* __restrict__ aux) {
  int s = 0;
#pragma unroll
  for (int e = 0; e < NE; ++e) s += min(counts[e], CAP);
  *aux = 0.01f * (float)s / (float)NTOK;
}

// ------------- gather expert inputs to fp16 (zero-fill unused slots) -------------
__global__ __launch_bounds__(256) void k_gather(const float* __restrict__ x,
                                                const int* __restrict__ slot_tok,
                                                _Float16* __restrict__ xg) {
  int row = blockIdx.x;
  int tok = slot_tok[row];
  int t = threadIdx.x;
  f16x4 h;
  if (tok >= 0) {
    float4 v = *(const float4*)(x + (size_t)tok * DM + t * 4);
    h[0] = (_Float16)v.x; h[1] = (_Float16)v.y; h[2] = (_Float16)v.z; h[3] = (_Float16)v.w;
  } else {
    h[0] = (_Float16)0.f; h[1] = (_Float16)0.f; h[2] = (_Float16)0.f; h[3] = (_Float16)0.f;
  }
  *(f16x4*)(xg + (size_t)row * DM + t * 4) = h;
}

// ------------- transpose+convert: W[e][K][N] fp32 -> WT[e][N][K] fp16 -------------
__global__ __launch_bounds__(256) void k_transpose(const float* __restrict__ W,
                                                   _Float16* __restrict__ WT,
                                                   int K, int N) {
  __shared__ float tile[64][65];
  int e = blockIdx.z;
  int n0 = blockIdx.x * 64, k0 = blockIdx.y * 64;
  const float* src = W + ((size_t)e * K + k0) * N + n0;
  int t = threadIdx.x;
  int kr = t >> 4, nc = (t & 15) * 4;
#pragma unroll
  for (int r = 0; r < 4; ++r) {
    int row = r * 16 + kr;
    float4 v = *(const float4*)(src + (size_t)row * N + nc);
    tile[row][nc + 0] = v.x; tile[row][nc + 1] = v.y;
    tile[row][nc + 2] = v.z; tile[row][nc + 3] = v.w;
  }
  __syncthreads();
  int nr = t >> 3, kc = (t & 7) * 8;
  size_t dstbase = ((size_t)e * N + n0) * (size_t)K + k0;
#pragma unroll
  for (int r = 0; r < 2; ++r) {
    int n = r * 32 + nr;
    f16x8 h;
#pragma unroll
    for (int j = 0; j < 8; ++j) h[j] = (_Float16)tile[kc + j][n];
    *(f16x8*)(WT + dstbase + (size_t)n * K + kc) = h;
  }
}

// ==================== fp16 MFMA GEMMs: 256x256 tile, BK=64, 8 waves, LDS dbuf ====================
// LDS: 2 buffers x (A 256x64 + B 256x64) fp16 = 131072 B. 16B chunks XOR-swizzled (c ^= row&7);
// global_load_lds writes linearly, so the GLOBAL source address is pre-swizzled.
// Counted vmcnt(8) keeps next k-tile's 8 loads/thread in flight across the barrier.

__device__ __forceinline__ void stage256(const _Float16* gb, int ld, int kk,
                                         _Float16* lds, int w, int lane, int rowlim) {
#pragma unroll
  for (int i = 0; i < 4; ++i) {
    int ci = (w * 4 + i) * 64 + lane;
    int row = ci >> 3, c = ci & 7;
    int cs = c ^ (row & 7);
    int rc = row < rowlim ? row : rowlim;
    gload16(gb + (size_t)rc * ld + kk + cs * 8, lds + (w * 4 + i) * 512);
  }
}

#define GEMM_CORE(As, Bs)                                                            \
  {                                                                                  \
    _Pragma("unroll")                                                                \
    for (int ks = 0; ks < 2; ++ks) {                                                 \
      f16x8 af[8], bf[4];                                                            \
      _Pragma("unroll")                                                              \
      for (int m = 0; m < 8; ++m) {                                                  \
        int row = wr * 128 + m * 16 + lr;                                            \
        af[m] = *(const f16x8*)((As) + row * 64 + (((ks * 4 + kg) ^ (row & 7)) << 3)); \
      }                                                                              \
      _Pragma("unroll")                                                              \
      for (int n = 0; n < 4; ++n) {                                                  \
        int row = wc * 64 + n * 16 + lr;                                             \
        bf[n] = *(const f16x8*)((Bs) + row * 64 + (((ks * 4 + kg) ^ (row & 7)) << 3)); \
      }                                                                              \
      _Pragma("unroll")                                                              \
      for (int m = 0; m < 8; ++m)                                                    \
        _Pragma("unroll")                                                            \
        for (int n = 0; n < 4; ++n)                                                  \
          acc[m][n] = __builtin_amdgcn_mfma_f32_16x16x32_f16(af[m], bf[n], acc[m][n], 0, 0, 0); \
    }                                                                                \
  }

// ---- GEMM1: h = gelu(xg @ W1T^T + b1); grid 3m x 16n x 16e = 768 blocks ----
__global__ __launch_bounds__(512, 2) void k_mm1(const _Float16* __restrict__ xg,
                                                const _Float16* __restrict__ W1T,
                                                const float* __restrict__ b1,
                                                _Float16* __restrict__ hbuf) {
  extern __shared__ _Float16 sm[];
  int bid = blockIdx.x;
  int L = (bid & 7) * 96 + (bid >> 3);
  int my = L % 3;
  int nx = (L / 3) & 15;
  int e  = L / 48;
  int m0 = my * 256, n0 = nx * 256;
  const _Float16* Ab = xg  + ((size_t)e * CAP + m0) * DM;
  const _Float16* Bb = W1T + ((size_t)e * HD  + n0) * DM;
  int alim = CAP - 1 - m0;                 // clamp pad rows to last real row

  int tid = threadIdx.x, lane = tid & 63, w = tid >> 6;
  int wr = w >> 2, wc = w & 3;
  int lr = lane & 15, kg = lane >> 4, lq = kg;

  f32x4 acc[8][4];
#pragma unroll
  for (int m = 0; m < 8; ++m)
#pragma unroll
    for (int n = 0; n < 4; ++n) acc[m][n] = (f32x4){0.f, 0.f, 0.f, 0.f};

  stage256(Ab, DM, 0, sm, w, lane, alim);
  stage256(Bb, DM, 0, sm + 16384, w, lane, 255);
  for (int t = 0; t < 16; ++t) {
    if (t < 15) {
      _Float16* nb = sm + ((t + 1) & 1) * 32768;
      stage256(Ab, DM, (t + 1) * 64, nb, w, lane, alim);
      stage256(Bb, DM, (t + 1) * 64, nb + 16384, w, lane, 255);
      asm volatile("s_waitcnt vmcnt(8)" ::: "memory");
    } else {
      asm volatile("s_waitcnt vmcnt(0)" ::: "memory");
    }
    __builtin_amdgcn_s_barrier();
    __builtin_amdgcn_sched_barrier(0);
    const _Float16* As = sm + (t & 1) * 32768;
    const _Float16* Bs = As + 16384;
    GEMM_CORE(As, Bs);
    __builtin_amdgcn_s_barrier();
    __builtin_amdgcn_sched_barrier(0);
  }

  // epilogue: bias + exact GELU -> fp16, bounce via LDS (256x256) for coalesced stores
  __syncthreads();
  _Float16* Cb = sm;
  float bias[4];
#pragma unroll
  for (int n = 0; n < 4; ++n)
    bias[n] = b1[(size_t)e * HD + n0 + wc * 64 + n * 16 + lr];
#pragma unroll
  for (int m = 0; m < 8; ++m) {
#pragma unroll
    for (int n = 0; n < 4; ++n) {
#pragma unroll
      for (int r = 0; r < 4; ++r) {
        int row = wr * 128 + m * 16 + lq * 4 + r;
        int col = wc * 64 + n * 16 + lr;
        float v = acc[m][n][r] + bias[n];
        v = 0.5f * v * (1.0f + erff(v * 0.70710678118654752f));
        Cb[row * 256 + (col ^ (((row >> 2) & 3) << 4))] = (_Float16)v;
      }
    }
  }
  __syncthreads();
  int r8 = tid >> 5, c8 = (tid & 31) * 8;
#pragma unroll
  for (int p = 0; p < 16; ++p) {
    int row = p * 16 + r8;
    if (m0 + row < CAP) {
      int colx = c8 ^ (((row >> 2) & 3) << 4);
      f16x8 v = *(const f16x8*)(Cb + row * 256 + colx);
      *(f16x8*)(hbuf + ((size_t)e * CAP + m0 + row) * HD + n0 + c8) = v;
    }
  }
}

// ---- GEMM2: y[tok] += w*(h @ W2T^T + b2); K split 4; grid 3m x 4n x 4ks x 16e = 768 ----
__global__ __launch_bounds__(512, 2) void k_mm2(const _Float16* __restrict__ hbuf,
                                                const _Float16* __restrict__ W2T,
                                                const float* __restrict__ b2,
                                                const int* __restrict__ slot_tok,
                                                const float* __restrict__ slot_w,
                                                float* __restrict__ y) {
  extern __shared__ _Float16 sm[];
  int bid = blockIdx.x;
  int L = (bid & 7) * 96 + (bid >> 3);
  int my = L % 3;
  int ks4 = (L / 3) & 3;
  int nx  = (L / 12) & 3;
  int e   = L / 48;
  int m0 = my * 256, n0 = nx * 256, kbase = ks4 * 1024;
  const _Float16* Ab = hbuf + ((size_t)e * CAP + m0) * HD;
  const _Float16* Bb = W2T  + ((size_t)e * DM  + n0) * HD;
  int alim = CAP - 1 - m0;

  int tid = threadIdx.x, lane = tid & 63, w = tid >> 6;
  int wr = w >> 2, wc = w & 3;
  int lr = lane & 15, kg = lane >> 4, lq = kg;

  f32x4 acc[8][4];
#pragma unroll
  for (int m = 0; m < 8; ++m)
#pragma unroll
    for (int n = 0; n < 4; ++n) acc[m][n] = (f32x4){0.f, 0.f, 0.f, 0.f};

  stage256(Ab, HD, kbase, sm, w, lane, alim);
  stage256(Bb, HD, kbase, sm + 16384, w, lane, 255);
  for (int t = 0; t < 16; ++t) {
    if (t < 15) {
      _Float16* nb = sm + ((t + 1) & 1) * 32768;
      stage256(Ab, HD, kbase + (t + 1) * 64, nb, w, lane, alim);
      stage256(Bb, HD, kbase + (t + 1) * 64, nb + 16384, w, lane, 255);
      asm volatile("s_waitcnt vmcnt(8)" ::: "memory");
    } else {
      asm volatile("s_waitcnt vmcnt(0)" ::: "memory");
    }
    __builtin_amdgcn_s_barrier();
    __builtin_amdgcn_sched_barrier(0);
    const _Float16* As = sm + (t & 1) * 32768;
    const _Float16* Bs = As + 16384;
    GEMM_CORE(As, Bs);
    __builtin_amdgcn_s_barrier();
    __builtin_amdgcn_sched_barrier(0);
  }

  // epilogue: bias (only ks==0), gate weight, atomic scatter-combine
  float bias[4];
#pragma unroll
  for (int n = 0; n < 4; ++n)
    bias[n] = (ks4 == 0) ? b2[(size_t)e * DM + n0 + wc * 64 + n * 16 + lr] : 0.f;
#pragma unroll
  for (int m = 0; m < 8; ++m) {
#pragma unroll
    for (int r = 0; r < 4; ++r) {
      int rowg = m0 + wr * 128 + m * 16 + lq * 4 + r;
      if (rowg < CAP) {
        int tk = slot_tok[e * CAP + rowg];
        if (tk >= 0) {
          float wgt = slot_w[e * CAP + rowg];
#pragma unroll
          for (int n = 0; n < 4; ++n) {
            int col = n0 + wc * 64 + n * 16 + lr;
            atomicAdd(&y[(size_t)tk * DM + col], wgt * (acc[m][n][r] + bias[n]));
          }
        }
      }
    }
  }
}

extern "C" void kernel_launch(void* const* d_in, const int* in_sizes, int n_in,
                              void* d_out, int out_size, void* d_ws, size_t ws_size,
                              hipStream_t stream) {
  const float* x  = (const float*)d_in[0];
  const float* Wr = (const float*)d_in[1];
  const float* W1 = (const float*)d_in[2];
  const float* b1 = (const float*)d_in[3];
  const float* W2 = (const float*)d_in[4];
  const float* b2 = (const float*)d_in[5];
  float* y = (float*)d_out;
  float* aux = y + (size_t)out_size - 1;

  char* ws = (char*)d_ws;
  float* probs    = (float*)ws; ws += (size_t)NTOK * NE * 4;   // 512 KB
  float* P0       = (float*)ws; ws += 32 * NE * 4;
  float* P1       = (float*)ws; ws += 32 * NE * 4;
  int*   eidx     = (int*)ws;   ws += NTOK * 2 * 4;
  float* ew       = (float*)ws; ws += NTOK * 2 * 4;
  int*   slot_tok = (int*)ws;   ws += NE * CAP * 4;
  float* slot_w   = (float*)ws; ws += NE * CAP * 4;
  int*   counts   = (int*)ws;   ws += 256;
  _Float16* xg    = (_Float16*)ws; ws += (size_t)NE * CAP * DM * 2;   // 20 MB
  _Float16* hbuf  = (_Float16*)ws; ws += (size_t)NE * CAP * HD * 2;   // 80 MB
  _Float16* WT    = (_Float16*)ws;                                    // 128 MB (shared W1T/W2T)

  hipFuncSetAttribute((const void*)k_mm1, hipFuncAttributeMaxDynamicSharedMemorySize, 131072);
  hipFuncSetAttribute((const void*)k_mm2, hipFuncAttributeMaxDynamicSharedMemorySize, 131072);

  hipMemsetAsync(d_out, 0, (size_t)out_size * 4, stream);
  hipMemsetAsync(slot_tok, 0xFF, (size_t)NE * CAP * 4, stream);

  k_router<<<NTOK / 4, 256, 0, stream>>>(x, Wr, probs, P0);
  k_sink<<<32, 256, 0, stream>>>(probs, P0, P1);
  k_sink<<<32, 256, 0, stream>>>(probs, P1, P0);
  k_sink3<<<32, 256, 0, stream>>>(probs, P0, eidx, ew);
  k_scan<<<NE, 256, 0, stream>>>(eidx, ew, slot_tok, slot_w, counts);
  k_aux<<<1, 1, 0, stream>>>(counts, aux);
  k_gather<<<NE * CAP, 256, 0, stream>>>(x, slot_tok, xg);

  dim3 t1(HD / 64, DM / 64, NE);
  k_transpose<<<t1, 256, 0, stream>>>(W1, WT, DM, HD);
  k_mm1<<<768, 512, 131072, stream>>>(xg, WT, b1, hbuf);

  dim3 t2(DM / 64, HD / 64, NE);
  k_transpose<<<t2, 256, 0, stream>>>(W2, WT, HD, DM);
  k_mm2<<<768, 512, 131072, stream>>>(hbuf, WT, b2, slot_tok, slot_w, y);
}